// Round 1
// baseline (347.872 us; speedup 1.0000x reference)
//
#include <hip/hip_runtime.h>

// Problem constants (from reference)
#define N_SRC 100000
#define N_MID 20000
#define N_OUT 5000
#define E_1   20000
#define E_2   20000
#define DIN   64
#define DH    64
#define DEF   32

#define ET 64          // edges per block tile
#define NSPLIT 3       // f-splits of 11 each (covers f=0..32, f==32 -> bias)

// Fused NNConv message GEMM + atomic scatter.
// msg[e,o] = sum_f ef[e,f] * sum_i h[src[e],i] * W[f*4096 + i*64 + o]
//          + sum_i h[src[e],i] * b[i*64 + o]
__global__ __launch_bounds__(256) void nnconv_kernel(
    const float* __restrict__ h,      // [n_src_rows, 64]
    const float* __restrict__ efeat,  // [E, 32]
    const float* __restrict__ W,      // [32*4096] flat
    const float* __restrict__ b,      // [4096]
    const int*  __restrict__ src,
    const int*  __restrict__ dst,
    int E,
    float* __restrict__ sums)         // [n_dst, 64] atomic accum
{
    __shared__ float hsT[64][ET + 4];   // hsT[i][e], +4 pad keeps float4 alignment
    __shared__ float efs[ET][DEF + 1];  // efs[e][f]
    __shared__ float Wl[64 * 64];       // Wl[i*64 + o], one f-slab (16 KB)

    const int t     = threadIdx.x;
    const int ebase = blockIdx.x * ET;
    const int split = blockIdx.y;

    // ---- stage gathered source features, transposed: hsT[i][e] ----
    #pragma unroll
    for (int c = 0; c < 16; ++c) {
        int idx = c * 256 + t;          // 0..4095
        int e = idx >> 6, i = idx & 63;
        int eg = ebase + e;
        float v = 0.0f;
        if (eg < E) v = h[(size_t)src[eg] * 64 + i];   // coalesced row read
        hsT[i][e] = v;
    }
    // ---- stage edge features: efs[e][f] ----
    #pragma unroll
    for (int c = 0; c < 8; ++c) {
        int idx = c * 256 + t;          // 0..2047
        int e = idx >> 5, f = idx & 31;
        int eg = ebase + e;
        efs[e][f] = (eg < E) ? efeat[eg * 32 + f] : 0.0f;
    }

    const int og = t & 15;              // 16 col groups
    const int eg4 = t >> 4;             // 16 edge groups
    const int o0 = og * 4;
    const int e0 = eg4 * 4;

    float acc[4][4] = {};

    const int f_lo = split * 11;
    const int f_hi = f_lo + 11;         // split 2 ends at 33; f==32 is the bias chunk

    for (int f = f_lo; f < f_hi; ++f) {
        __syncthreads();                // Wl from previous iter fully consumed; staging done (iter 1)
        const float4* src4 = (const float4*)((f < 32) ? (W + (size_t)f * 4096) : b);
        float4* wl4 = (float4*)Wl;
        #pragma unroll
        for (int c = 0; c < 4; ++c)
            wl4[c * 256 + t] = src4[c * 256 + t];
        __syncthreads();

        float efv0, efv1, efv2, efv3;
        if (f < 32) {
            efv0 = efs[e0 + 0][f];
            efv1 = efs[e0 + 1][f];
            efv2 = efs[e0 + 2][f];
            efv3 = efs[e0 + 3][f];
        } else {
            efv0 = efv1 = efv2 = efv3 = 1.0f;   // bias chunk
        }

        #pragma unroll
        for (int i = 0; i < 64; ++i) {
            float4 wv = *(const float4*)&Wl[i * 64 + o0];
            float4 hv = *(const float4*)&hsT[i][e0];
            float t0 = efv0 * hv.x;
            float t1 = efv1 * hv.y;
            float t2 = efv2 * hv.z;
            float t3 = efv3 * hv.w;
            acc[0][0] += t0 * wv.x; acc[0][1] += t0 * wv.y; acc[0][2] += t0 * wv.z; acc[0][3] += t0 * wv.w;
            acc[1][0] += t1 * wv.x; acc[1][1] += t1 * wv.y; acc[1][2] += t1 * wv.z; acc[1][3] += t1 * wv.w;
            acc[2][0] += t2 * wv.x; acc[2][1] += t2 * wv.y; acc[2][2] += t2 * wv.z; acc[2][3] += t2 * wv.w;
            acc[3][0] += t3 * wv.x; acc[3][1] += t3 * wv.y; acc[3][2] += t3 * wv.z; acc[3][3] += t3 * wv.w;
        }
    }

    // ---- scatter-add into destination sums ----
    #pragma unroll
    for (int j = 0; j < 4; ++j) {
        int eg = ebase + e0 + j;
        if (eg < E) {
            float* p = sums + (size_t)dst[eg] * 64 + o0;
            atomicAdd(p + 0, acc[j][0]);
            atomicAdd(p + 1, acc[j][1]);
            atomicAdd(p + 2, acc[j][2]);
            atomicAdd(p + 3, acc[j][3]);
        }
    }
}

__global__ void count_kernel(const int* __restrict__ dst1, const int* __restrict__ dst2,
                             float* __restrict__ cnt1, float* __restrict__ cnt2)
{
    int i = blockIdx.x * blockDim.x + threadIdx.x;
    if (i < E_1) atomicAdd(&cnt1[dst1[i]], 1.0f);
    else if (i < E_1 + E_2) atomicAdd(&cnt2[dst2[i - E_1]], 1.0f);
}

// in-place: sums[n,o] /= max(cnt[n],1); optional relu
__global__ void norm_kernel(float* __restrict__ sums, const float* __restrict__ cnt,
                            int n_nodes, int do_relu)
{
    int idx = blockIdx.x * blockDim.x + threadIdx.x;   // float4 index
    int total = n_nodes * 16;
    if (idx >= total) return;
    int node = idx >> 4;
    float c = fmaxf(cnt[node], 1.0f);
    float4 v = ((float4*)sums)[idx];
    v.x /= c; v.y /= c; v.z /= c; v.w /= c;
    if (do_relu) {
        v.x = fmaxf(v.x, 0.0f); v.y = fmaxf(v.y, 0.0f);
        v.z = fmaxf(v.z, 0.0f); v.w = fmaxf(v.w, 0.0f);
    }
    ((float4*)sums)[idx] = v;
}

extern "C" void kernel_launch(void* const* d_in, const int* in_sizes, int n_in,
                              void* d_out, int out_size, void* d_ws, size_t ws_size,
                              hipStream_t stream)
{
    const float* in_feat = (const float*)d_in[0];
    const float* ef1     = (const float*)d_in[1];
    const float* ef2     = (const float*)d_in[2];
    const float* W1      = (const float*)d_in[3];
    const float* b1      = (const float*)d_in[4];
    const float* W2      = (const float*)d_in[5];
    const float* b2      = (const float*)d_in[6];
    const int*   src1    = (const int*)d_in[7];
    const int*   dst1    = (const int*)d_in[8];
    const int*   src2    = (const int*)d_in[9];
    const int*   dst2    = (const int*)d_in[10];

    float* h_mid = (float*)d_ws;                 // [20000*64], also holds sums1
    float* cnt1  = h_mid + (size_t)N_MID * 64;   // [20000]
    float* cnt2  = cnt1 + N_MID;                 // [5000]
    float* out   = (float*)d_out;                // [5000*64], holds sums2 then result

    // harness poisons ws/out with 0xAA before every launch -> zero what we accumulate into
    size_t zero_bytes = ((size_t)N_MID * 64 + N_MID + N_OUT) * sizeof(float);
    hipMemsetAsync(d_ws, 0, zero_bytes, stream);
    hipMemsetAsync(d_out, 0, (size_t)N_OUT * 64 * sizeof(float), stream);

    count_kernel<<<(E_1 + E_2 + 255) / 256, 256, 0, stream>>>(dst1, dst2, cnt1, cnt2);

    dim3 grid((E_1 + ET - 1) / ET, NSPLIT);
    nnconv_kernel<<<grid, 256, 0, stream>>>(in_feat, ef1, W1, b1, src1, dst1, E_1, h_mid);
    norm_kernel<<<(N_MID * 16 + 255) / 256, 256, 0, stream>>>(h_mid, cnt1, N_MID, 1);

    nnconv_kernel<<<grid, 256, 0, stream>>>(h_mid, ef2, W2, b2, src2, dst2, E_2, out);
    norm_kernel<<<(N_OUT * 16 + 255) / 256, 256, 0, stream>>>(out, cnt2, N_OUT, 0);
}

// Round 2
// 148.250 us; speedup vs baseline: 2.3465x; 2.3465x over previous
//
#include <hip/hip_runtime.h>
#include <hip/hip_bf16.h>

// Problem constants
#define N_SRC 100000
#define N_MID 20000
#define N_OUT 5000
#define E_1   20000
#define E_2   20000
#define NCHUNK 33      // 32 W chunks + 1 bias chunk

typedef float f32x4 __attribute__((ext_vector_type(4)));
typedef short s16x8 __attribute__((ext_vector_type(8)));   // 8 bf16 = 4 VGPRs (guide §3)

__device__ __forceinline__ void load_lds16(const void* g, void* l) {
    __builtin_amdgcn_global_load_lds(
        (const __attribute__((address_space(1))) unsigned int*)g,
        (__attribute__((address_space(3))) unsigned int*)l, 16, 0, 0);
}

__device__ __forceinline__ s16x8 pack_bf16x8(float4 x, float4 y, float s) {
    union { s16x8 v; __hip_bfloat162 h[4]; } u;
    u.h[0] = __float22bfloat162_rn(make_float2(s * x.x, s * x.y));
    u.h[1] = __float22bfloat162_rn(make_float2(s * x.z, s * x.w));
    u.h[2] = __float22bfloat162_rn(make_float2(s * y.x, s * y.y));
    u.h[3] = __float22bfloat162_rn(make_float2(s * y.z, s * y.w));
    return u.v;
}

__device__ __forceinline__ unsigned short f2bf_rne(float f) {
    unsigned u = __float_as_uint(f);
    return (unsigned short)((u + 0x7FFFu + ((u >> 16) & 1u)) >> 16);
}

// Pre-convert W (fp32 [32][64i][64o]) + bias into bf16, B^T-style [chunk][n(o)][k(i)]
// layout in 16B units, XOR-swizzled so global_load_lds's linear write yields
// conflict-free B-frag ds_read_b128:  unit(n,k8) -> n*8 + (k8 ^ (n&7)).
__global__ void prep_kernel(const float* __restrict__ W1, const float* __restrict__ b1,
                            const float* __restrict__ W2, const float* __restrict__ b2,
                            uint4* __restrict__ Wt1, uint4* __restrict__ Wt2)
{
    int gid = blockIdx.x * 256 + threadIdx.x;     // 0 .. 2*33*512-1
    if (gid >= 2 * NCHUNK * 512) return;
    int layer = gid / (NCHUNK * 512);
    int r     = gid % (NCHUNK * 512);
    int c  = r / 512;
    int u  = r % 512;
    int k8 = u / 64;        // 0..7  (8 bf16 k-group)
    int n  = u % 64;        // output col — fastest => coalesced reads
    const float* W = layer ? W2 : W1;
    const float* b = layer ? b2 : b1;
    const float* s = (c < 32) ? (W + (size_t)c * 4096) : b;
    union { uint4 v; unsigned short us[8]; } pk;
    #pragma unroll
    for (int j = 0; j < 8; ++j)
        pk.us[j] = f2bf_rne(s[(k8 * 8 + j) * 64 + n]);
    uint4* Wt = layer ? Wt2 : Wt1;
    Wt[(size_t)c * 512 + n * 8 + (k8 ^ (n & 7))] = pk.v;
}

// Fused NNConv message GEMM (MFMA) + atomic scatter.
// msg[e,o] = sum_{f<32} ef[e,f] * (hs[e,:] @ Wf) + hs[e,:] @ b   (chunk 32, ef=1)
__global__ __launch_bounds__(256) void nnconv_mfma(
    const float* __restrict__ h,      // [n_rows, 64] fp32
    const float* __restrict__ efeat,  // [E, 32] fp32
    const uint4* __restrict__ Wt,     // [33][512] swizzled bf16 units
    const int*  __restrict__ src,
    const int*  __restrict__ dst,
    int E,
    float* __restrict__ sums)         // [n_dst, 64] atomic accum
{
    __shared__ float efs[64][34];         // [edge][f], f=32 is bias col (1.0)
    __shared__ uint4 wbuf[2][512];        // double-buffered W chunk (8 KB each)

    const int t  = threadIdx.x;
    const int w  = t >> 6;                // wave 0..3
    const int l  = t & 63;                // lane
    const int m15 = l & 15;               // MFMA row (A) / col (B,C)
    const int q   = l >> 4;               // quad 0..3
    const int ebase = blockIdx.x * 64;
    const int split = blockIdx.y;
    const int c_lo = split ? 17 : 0;
    const int c_hi = split ? 33 : 17;

    // ---- stage edge features (+bias col) ----
    for (int idx = t; idx < 64 * 33; idx += 256) {
        int e = idx / 33, f = idx % 33;
        int eg = ebase + e;
        float v = 0.0f;
        if (eg < E) v = (f < 32) ? efeat[eg * 32 + f] : 1.0f;
        efs[e][f] = v;
    }

    // ---- issue first W chunk into wbuf[0] ----
    {
        const uint4* g = Wt + (size_t)c_lo * 512;
        load_lds16(g + t,       &wbuf[0][t]);
        load_lds16(g + 256 + t, &wbuf[0][256 + t]);
    }

    // ---- A-frag fp32 preload from global (gather, once per block) ----
    // lane holds hs[e = ebase+w*16+m15][k], k = q*8..q*8+7 (s=0) and +32 (s=1)
    const int e_a = ebase + w * 16 + m15;
    const int row = (e_a < E) ? src[e_a] : 0;
    const float* hp = h + (size_t)row * 64 + q * 8;
    const float4 ha0 = *(const float4*)(hp);
    const float4 ha1 = *(const float4*)(hp + 4);
    const float4 hb0 = *(const float4*)(hp + 32);
    const float4 hb1 = *(const float4*)(hp + 36);

    f32x4 acc[4] = {};
    const int nx = m15 & 7;

    int cur = 0;
    for (int c = c_lo; c < c_hi; ++c) {
        __syncthreads();                          // wbuf[cur] resident (barrier drains vmcnt)
        if (c + 1 < c_hi) {
            const uint4* g = Wt + (size_t)(c + 1) * 512;
            load_lds16(g + t,       &wbuf[cur ^ 1][t]);
            load_lds16(g + 256 + t, &wbuf[cur ^ 1][256 + t]);
        }
        const float ef = efs[w * 16 + m15][c];
        const s16x8 a0 = pack_bf16x8(ha0, ha1, ef);   // kstep 0
        const s16x8 a1 = pack_bf16x8(hb0, hb1, ef);   // kstep 1
        const uint4* wb = wbuf[cur];
        #pragma unroll
        for (int c16 = 0; c16 < 4; ++c16) {
            const int n = c16 * 16 + m15;
            const s16x8 b0 = *(const s16x8*)&wb[n * 8 + ((q)     ^ nx)];
            const s16x8 b1 = *(const s16x8*)&wb[n * 8 + ((4 + q) ^ nx)];
            acc[c16] = __builtin_amdgcn_mfma_f32_16x16x32_bf16(a0, b0, acc[c16], 0, 0, 0);
            acc[c16] = __builtin_amdgcn_mfma_f32_16x16x32_bf16(a1, b1, acc[c16], 0, 0, 0);
        }
        cur ^= 1;
    }

    // ---- scatter-add: lane holds D[m=q*4+r][n=c16*16+m15] ----
    int drow[4]; bool dval[4];
    #pragma unroll
    for (int r = 0; r < 4; ++r) {
        int e = ebase + w * 16 + q * 4 + r;
        dval[r] = (e < E);
        drow[r] = dval[r] ? dst[e] : 0;
    }
    #pragma unroll
    for (int c16 = 0; c16 < 4; ++c16)
        #pragma unroll
        for (int r = 0; r < 4; ++r)
            if (dval[r])
                atomicAdd(&sums[(size_t)drow[r] * 64 + c16 * 16 + m15], acc[c16][r]);
}

__global__ void count_kernel(const int* __restrict__ dst1, const int* __restrict__ dst2,
                             float* __restrict__ cnt1, float* __restrict__ cnt2)
{
    int i = blockIdx.x * blockDim.x + threadIdx.x;
    if (i < E_1) atomicAdd(&cnt1[dst1[i]], 1.0f);
    else if (i < E_1 + E_2) atomicAdd(&cnt2[dst2[i - E_1]], 1.0f);
}

__global__ void norm_kernel(float* __restrict__ sums, const float* __restrict__ cnt,
                            int n_nodes, int do_relu)
{
    int idx = blockIdx.x * blockDim.x + threadIdx.x;   // float4 index
    int total = n_nodes * 16;
    if (idx >= total) return;
    int node = idx >> 4;
    float c = fmaxf(cnt[node], 1.0f);
    float inv = 1.0f / c;
    float4 v = ((float4*)sums)[idx];
    v.x *= inv; v.y *= inv; v.z *= inv; v.w *= inv;
    if (do_relu) {
        v.x = fmaxf(v.x, 0.0f); v.y = fmaxf(v.y, 0.0f);
        v.z = fmaxf(v.z, 0.0f); v.w = fmaxf(v.w, 0.0f);
    }
    ((float4*)sums)[idx] = v;
}

extern "C" void kernel_launch(void* const* d_in, const int* in_sizes, int n_in,
                              void* d_out, int out_size, void* d_ws, size_t ws_size,
                              hipStream_t stream)
{
    const float* in_feat = (const float*)d_in[0];
    const float* ef1     = (const float*)d_in[1];
    const float* ef2     = (const float*)d_in[2];
    const float* W1      = (const float*)d_in[3];
    const float* b1      = (const float*)d_in[4];
    const float* W2      = (const float*)d_in[5];
    const float* b2      = (const float*)d_in[6];
    const int*   src1    = (const int*)d_in[7];
    const int*   dst1    = (const int*)d_in[8];
    const int*   src2    = (const int*)d_in[9];
    const int*   dst2    = (const int*)d_in[10];

    float* h_mid = (float*)d_ws;                         // [20000*64] fp32 (sums1 then h)
    float* cnt1  = h_mid + (size_t)N_MID * 64;           // [20000]
    float* cnt2  = cnt1 + N_MID;                         // [5000]
    uint4* Wt1   = (uint4*)(cnt2 + N_OUT);               // [33*512] 16B units (offset 5,220,000 B, 16-aligned)
    uint4* Wt2   = Wt1 + (size_t)NCHUNK * 512;
    float* out   = (float*)d_out;                        // [5000*64]

    // zero accumulators (harness poisons ws/out with 0xAA)
    size_t zero_bytes = ((size_t)N_MID * 64 + N_MID + N_OUT) * sizeof(float);
    hipMemsetAsync(d_ws, 0, zero_bytes, stream);
    hipMemsetAsync(d_out, 0, (size_t)N_OUT * 64 * sizeof(float), stream);

    prep_kernel<<<(2 * NCHUNK * 512 + 255) / 256, 256, 0, stream>>>(W1, b1, W2, b2, Wt1, Wt2);
    count_kernel<<<(E_1 + E_2 + 255) / 256, 256, 0, stream>>>(dst1, dst2, cnt1, cnt2);

    dim3 grid((E_1 + 63) / 64, 2);
    nnconv_mfma<<<grid, 256, 0, stream>>>(in_feat, ef1, Wt1, src1, dst1, E_1, h_mid);
    norm_kernel<<<(N_MID * 16 + 255) / 256, 256, 0, stream>>>(h_mid, cnt1, N_MID, 1);

    nnconv_mfma<<<grid, 256, 0, stream>>>(h_mid, ef2, Wt2, src2, dst2, E_2, out);
    norm_kernel<<<(N_OUT * 16 + 255) / 256, 256, 0, stream>>>(out, cnt2, N_OUT, 0);
}

// Round 3
// 146.392 us; speedup vs baseline: 2.3763x; 1.0127x over previous
//
#include <hip/hip_runtime.h>
#include <hip/hip_bf16.h>

// Problem constants
#define N_SRC 100000
#define N_MID 20000
#define N_OUT 5000
#define E_1   20000
#define E_2   20000
#define NCHUNK 33      // 32 W chunks + 1 bias chunk
#define NSPLIT 4       // K-split: chunk ranges {0-9,9-17,17-25,25-33}
#define NBLK   313     // ceil(20000/64)
#define EPAD   (NBLK*64)   // 20032 padded edges
#define MAXDEG 32      // slot table stride (Poisson(4) tail: P(deg>=32) ~ 1e-20)

typedef float f32x4 __attribute__((ext_vector_type(4)));
typedef short s16x8 __attribute__((ext_vector_type(8)));   // 8 bf16 = 4 VGPRs

__device__ __forceinline__ void load_lds16(const void* g, void* l) {
    __builtin_amdgcn_global_load_lds(
        (const __attribute__((address_space(1))) unsigned int*)g,
        (__attribute__((address_space(3))) unsigned int*)l, 16, 0, 0);
}

__device__ __forceinline__ s16x8 pack_bf16x8(float4 x, float4 y, float s) {
    union { s16x8 v; __hip_bfloat162 h[4]; } u;
    u.h[0] = __float22bfloat162_rn(make_float2(s * x.x, s * x.y));
    u.h[1] = __float22bfloat162_rn(make_float2(s * x.z, s * x.w));
    u.h[2] = __float22bfloat162_rn(make_float2(s * y.x, s * y.y));
    u.h[3] = __float22bfloat162_rn(make_float2(s * y.z, s * y.w));
    return u.v;
}

__device__ __forceinline__ unsigned short f2bf_rne(float f) {
    unsigned u = __float_as_uint(f);
    return (unsigned short)((u + 0x7FFFu + ((u >> 16) & 1u)) >> 16);
}

// Pre-convert W (fp32 [32][64i][64o]) + bias into bf16, [chunk][n(o)][k(i)] in 16B
// units, XOR-swizzled: unit(n,k8) -> n*8 + (k8 ^ (n&7))  (conflict-free ds_read_b128).
__global__ void prep_kernel(const float* __restrict__ W1, const float* __restrict__ b1,
                            const float* __restrict__ W2, const float* __restrict__ b2,
                            uint4* __restrict__ Wt1, uint4* __restrict__ Wt2)
{
    int gid = blockIdx.x * 256 + threadIdx.x;
    if (gid >= 2 * NCHUNK * 512) return;
    int layer = gid / (NCHUNK * 512);
    int r     = gid % (NCHUNK * 512);
    int c  = r / 512;
    int u  = r % 512;
    int k8 = u / 64;
    int n  = u % 64;
    const float* W = layer ? W2 : W1;
    const float* b = layer ? b2 : b1;
    const float* s = (c < 32) ? (W + (size_t)c * 4096) : b;
    union { uint4 v; unsigned short us[8]; } pk;
    #pragma unroll
    for (int j = 0; j < 8; ++j)
        pk.us[j] = f2bf_rne(s[(k8 * 8 + j) * 64 + n]);
    uint4* Wt = layer ? Wt2 : Wt1;
    Wt[(size_t)c * 512 + n * 8 + (k8 ^ (n & 7))] = pk.v;
}

// Build per-dst edge lists (slot table) + degree counts for both layers.
__global__ void count_slot_kernel(const int* __restrict__ dst1, const int* __restrict__ dst2,
                                  int* __restrict__ cur1, int* __restrict__ slots1,
                                  int* __restrict__ cur2, int* __restrict__ slots2)
{
    int i = blockIdx.x * blockDim.x + threadIdx.x;
    if (i < E_1) {
        int d = dst1[i];
        int p = atomicAdd(&cur1[d], 1);
        if (p < MAXDEG) slots1[(size_t)d * MAXDEG + p] = i;
    } else if (i < E_1 + E_2) {
        int e = i - E_1;
        int d = dst2[e];
        int p = atomicAdd(&cur2[d], 1);
        if (p < MAXDEG) slots2[(size_t)d * MAXDEG + p] = e;
    }
}

// Phase A: fused NNConv message GEMM (MFMA), plain stores of per-split partials.
// msg[split][e][o] = sum_{c in split} ef[e,c] * (hs[e,:] @ Wc)   (c==32: bias, ef=1)
__global__ __launch_bounds__(256) void nnconv_mfma(
    const float* __restrict__ h,      // [n_rows, 64] fp32
    const float* __restrict__ efeat,  // [E, 32] fp32
    const uint4* __restrict__ Wt,     // [33][512] swizzled bf16 units
    const int*  __restrict__ src,
    int E,
    float* __restrict__ msg)          // [NSPLIT][EPAD][64]
{
    __shared__ float efs[64][9];          // [edge][c - c_lo], split range <= 9 chunks
    __shared__ uint4 wbuf[2][512];        // double-buffered W chunk (8 KB each)

    const int t  = threadIdx.x;
    const int w  = t >> 6;                // wave 0..3
    const int l  = t & 63;
    const int m15 = l & 15;               // MFMA row (A) / col (B,C)
    const int q   = l >> 4;               // quad 0..3
    const int ebase = blockIdx.x * 64;
    const int split = blockIdx.y;
    const int c_lo = (split == 0) ? 0 : (split * 8 + 1);
    const int c_hi = split * 8 + 9;
    const int nc   = c_hi - c_lo;         // 9 or 8

    // ---- stage this split's edge-feature columns (bias col -> 1.0) ----
    for (int idx = t; idx < 64 * nc; idx += 256) {
        int e = idx / nc, j = idx - e * nc;
        int eg = ebase + e, f = c_lo + j;
        float v = 0.0f;
        if (eg < E) v = (f < 32) ? efeat[eg * 32 + f] : 1.0f;
        efs[e][j] = v;
    }

    // ---- issue first W chunk into wbuf[0] ----
    {
        const uint4* g = Wt + (size_t)c_lo * 512;
        load_lds16(g + t,       &wbuf[0][t]);
        load_lds16(g + 256 + t, &wbuf[0][256 + t]);
    }

    // ---- A-frag fp32 preload (gather, once per block) ----
    const int e_a = ebase + w * 16 + m15;
    const int row = (e_a < E) ? src[e_a] : 0;
    const float* hp = h + (size_t)row * 64 + q * 8;
    const float4 ha0 = *(const float4*)(hp);
    const float4 ha1 = *(const float4*)(hp + 4);
    const float4 hb0 = *(const float4*)(hp + 32);
    const float4 hb1 = *(const float4*)(hp + 36);

    f32x4 acc[4] = {};
    const int nx = m15 & 7;

    int cur = 0;
    for (int c = c_lo; c < c_hi; ++c) {
        __syncthreads();                          // wbuf[cur] resident
        if (c + 1 < c_hi) {
            const uint4* g = Wt + (size_t)(c + 1) * 512;
            load_lds16(g + t,       &wbuf[cur ^ 1][t]);
            load_lds16(g + 256 + t, &wbuf[cur ^ 1][256 + t]);
        }
        const float ef = efs[w * 16 + m15][c - c_lo];
        const s16x8 a0 = pack_bf16x8(ha0, ha1, ef);   // k 0..31
        const s16x8 a1 = pack_bf16x8(hb0, hb1, ef);   // k 32..63
        const uint4* wb = wbuf[cur];
        #pragma unroll
        for (int c16 = 0; c16 < 4; ++c16) {
            const int n = c16 * 16 + m15;
            const s16x8 b0 = *(const s16x8*)&wb[n * 8 + ((q)     ^ nx)];
            const s16x8 b1 = *(const s16x8*)&wb[n * 8 + ((4 + q) ^ nx)];
            acc[c16] = __builtin_amdgcn_mfma_f32_16x16x32_bf16(a0, b0, acc[c16], 0, 0, 0);
            acc[c16] = __builtin_amdgcn_mfma_f32_16x16x32_bf16(a1, b1, acc[c16], 0, 0, 0);
        }
        cur ^= 1;
    }

    // ---- plain stores: lane holds D[m=q*4+r][n=c16*16+m15] ----
    float* mp = msg + (size_t)split * EPAD * 64;
    #pragma unroll
    for (int r = 0; r < 4; ++r) {
        float* rp = mp + (size_t)(ebase + w * 16 + q * 4 + r) * 64 + m15;  // e < EPAD always
        #pragma unroll
        for (int c16 = 0; c16 < 4; ++c16)
            rp[c16 * 16] = acc[c16][r];
    }
}

// Phase B: one wave per dst node; lane = output col. Sum split partials over
// the dst's edge list, divide by degree, optional ReLU. No atomics.
__global__ void gather_mean(const float* __restrict__ msg,   // [NSPLIT][EPAD][64]
                            const int* __restrict__ slots, const int* __restrict__ cur,
                            int n_dst, int do_relu, float* __restrict__ outp)
{
    int d = blockIdx.x * 4 + (threadIdx.x >> 6);
    int o = threadIdx.x & 63;
    if (d >= n_dst) return;
    int deg = cur[d];
    int dg = min(deg, MAXDEG);
    float s = 0.0f;
    for (int j = 0; j < dg; ++j) {
        int e = slots[(size_t)d * MAXDEG + j];     // wave-uniform -> broadcast
        const float* mrow = msg + (size_t)e * 64 + o;
        #pragma unroll
        for (int sp = 0; sp < NSPLIT; ++sp)
            s += mrow[(size_t)sp * EPAD * 64];
    }
    s *= 1.0f / fmaxf((float)deg, 1.0f);
    if (do_relu) s = fmaxf(s, 0.0f);
    outp[(size_t)d * 64 + o] = s;
}

extern "C" void kernel_launch(void* const* d_in, const int* in_sizes, int n_in,
                              void* d_out, int out_size, void* d_ws, size_t ws_size,
                              hipStream_t stream)
{
    const float* in_feat = (const float*)d_in[0];
    const float* ef1     = (const float*)d_in[1];
    const float* ef2     = (const float*)d_in[2];
    const float* W1      = (const float*)d_in[3];
    const float* b1      = (const float*)d_in[4];
    const float* W2      = (const float*)d_in[5];
    const float* b2      = (const float*)d_in[6];
    const int*   src1    = (const int*)d_in[7];
    const int*   dst1    = (const int*)d_in[8];
    const int*   src2    = (const int*)d_in[9];
    const int*   dst2    = (const int*)d_in[10];

    // Workspace layout (all 4B-typed; Wt offset is 16B-aligned: 8,420,000 B)
    float* h_mid  = (float*)d_ws;                        // [20000*64]
    int*   cur1   = (int*)(h_mid + (size_t)N_MID * 64);  // [20000]
    int*   cur2   = cur1 + N_MID;                        // [5000]
    int*   slots1 = cur2 + N_OUT;                        // [20000*32]
    int*   slots2 = slots1 + (size_t)N_MID * MAXDEG;     // [5000*32]
    uint4* Wt1    = (uint4*)(slots2 + (size_t)N_OUT * MAXDEG);
    uint4* Wt2    = Wt1 + (size_t)NCHUNK * 512;
    float* msg    = (float*)(Wt2 + (size_t)NCHUNK * 512);// [NSPLIT*EPAD*64]
    float* out    = (float*)d_out;                       // [5000*64]

    // only the cursors need zeroing (contiguous 25000 ints)
    hipMemsetAsync(cur1, 0, (size_t)(N_MID + N_OUT) * sizeof(int), stream);

    prep_kernel<<<(2 * NCHUNK * 512 + 255) / 256, 256, 0, stream>>>(W1, b1, W2, b2, Wt1, Wt2);
    count_slot_kernel<<<(E_1 + E_2 + 255) / 256, 256, 0, stream>>>(dst1, dst2,
                                                                   cur1, slots1, cur2, slots2);

    dim3 grid(NBLK, NSPLIT);
    nnconv_mfma<<<grid, 256, 0, stream>>>(in_feat, ef1, Wt1, src1, E_1, msg);
    gather_mean<<<(N_MID + 3) / 4, 256, 0, stream>>>(msg, slots1, cur1, N_MID, 1, h_mid);

    nnconv_mfma<<<grid, 256, 0, stream>>>(h_mid, ef2, Wt2, src2, E_2, msg);
    gather_mean<<<(N_OUT + 3) / 4, 256, 0, stream>>>(msg, slots2, cur2, N_OUT, 0, out);
}